// Round 2
// baseline (352.371 us; speedup 1.0000x reference)
//
#include <hip/hip_runtime.h>
#include <math.h>

#define NUM_BINS 100
#define EPS 1e-6f

// ws layout (uint32): [0..99] pos-bin counts, [100..199] neg-bin counts, [200] pos pixel count
#define WS_WORDS (2 * NUM_BINS + 1)

// LDS: 8-way replicated histogram (R8: neutral, kept — zero cost, and at
// 32 waves/CU more concurrent updaters make it cheap insurance).
#define NREP 8
#define SH_POSC (2 * NUM_BINS * NREP)          // 1600
#define SH_WORDS (SH_POSC + 1)                 // 1601 words = 6.4 KB

// native vector types: __builtin_nontemporal_load requires these (not HIP_vector_type)
typedef float  vfloat4 __attribute__((ext_vector_type(4)));
typedef float  vfloat2 __attribute__((ext_vector_type(2)));
typedef int    vint4   __attribute__((ext_vector_type(4)));
typedef int    vint2   __attribute__((ext_vector_type(2)));

__global__ void hml_init_ws(unsigned int* __restrict__ ws) {
    int i = blockIdx.x * blockDim.x + threadIdx.x;
    if (i < WS_WORDS) ws[i] = 0u;
}

// C=32 specialized. R6: NT loads (bypass L1 miss-tracking cap, 106 -> <78us).
// R9 single change: 2 px/thread via float2 (was 4 px via float4) ->
// 2048 blocks = 8 blocks/CU = 32 waves/CU (was 1024 blocks / 16 waves, a
// single 50%-occupancy generation). Doubles per-CU outstanding-read sources
// to hide ~900cy HBM latency on the L1-bypassing NT path; launch_bounds
// (256,8) pins <=64 VGPR (float2 path ~40, no spill).
__global__ __launch_bounds__(256, 8) void hml_hist32(
    const vfloat2* __restrict__ f0v, const vfloat2* __restrict__ f1v,
    const vint2* __restrict__ gt, unsigned int* __restrict__ ws, int hw2)
{
    __shared__ unsigned int sh[SH_WORDS];
    for (int i = threadIdx.x; i < SH_WORDS; i += 256) sh[i] = 0u;
    __syncthreads();

    const int idx = blockIdx.x * 256 + threadIdx.x;
    const int col = threadIdx.x & (NREP - 1);

    vint2 g = __builtin_nontemporal_load(&gt[idx]);
    float s0 = 0.f, s1 = 0.f;

    #pragma unroll
    for (int cg = 0; cg < 32; cg += 4) {
        vfloat2 a[4], b[4];
        #pragma unroll
        for (int j = 0; j < 4; ++j)
            a[j] = __builtin_nontemporal_load(&f0v[(size_t)(cg + j) * hw2 + idx]);
        #pragma unroll
        for (int j = 0; j < 4; ++j)
            b[j] = __builtin_nontemporal_load(&f1v[(size_t)(cg + j) * hw2 + idx]);
        #pragma unroll
        for (int j = 0; j < 4; ++j) {
            float e0 = a[j].x - b[j].x + EPS;
            float e1 = a[j].y - b[j].y + EPS;
            s0 = fmaf(e0, e0, s0);
            s1 = fmaf(e1, e1, s1);
        }
    }

    float d[2] = { sqrtf(s0), sqrtf(s1) };
    int gg[2] = { g.x, g.y };

    // pos-pixel count: shfl-reduce per wave, one LDS atomic per wave
    int posc = (gg[0] == 0) + (gg[1] == 0);
    for (int off = 32; off > 0; off >>= 1)
        posc += __shfl_down(posc, off, 64);
    if ((threadIdx.x & 63) == 0 && posc)
        atomicAdd(&sh[SH_POSC], (unsigned)posc);

    #pragma unroll
    for (int k = 0; k < 2; ++k) {
        float dd = d[k];
        // histc: values in [0,1] only (dd>=0 from sqrt); floor(d*100) clip 99
        if (dd <= 1.0f) {
            int bin = (int)(dd * (float)NUM_BINS);
            if (bin > NUM_BINS - 1) bin = NUM_BINS - 1;
            int logical = bin + ((gg[k] != 0) ? NUM_BINS : 0);
            atomicAdd(&sh[logical * NREP + col], 1u);
        }
    }

    __syncthreads();
    // flush: thread i (<200) merges the 8 replicas of logical bin i, one
    // global atomic per nonzero bin; thread 200 flushes the pos count.
    {
        int i = threadIdx.x;
        if (i < 2 * NUM_BINS) {
            unsigned v = 0;
            #pragma unroll
            for (int c = 0; c < NREP; ++c) v += sh[i * NREP + c];
            if (v) atomicAdd(&ws[i], v);
        } else if (i == 2 * NUM_BINS) {
            unsigned v = sh[SH_POSC];
            if (v) atomicAdd(&ws[2 * NUM_BINS], v);
        }
    }
}

// Generic fallback (any C, hw multiple of 4).
__global__ __launch_bounds__(256) void hml_hist_generic(
    const float* __restrict__ f0, const float* __restrict__ f1,
    const int* __restrict__ gt, unsigned int* __restrict__ ws,
    int hw, int C)
{
    __shared__ unsigned int sh[WS_WORDS];
    for (int i = threadIdx.x; i < WS_WORDS; i += blockDim.x) sh[i] = 0u;
    __syncthreads();

    const int hw4 = hw >> 2;
    const int idx = blockIdx.x * blockDim.x + threadIdx.x;

    if (idx < hw4) {
        const float4* __restrict__ f0v = (const float4*)f0;
        const float4* __restrict__ f1v = (const float4*)f1;
        float s0 = 0.f, s1 = 0.f, s2 = 0.f, s3 = 0.f;
        for (int c = 0; c < C; ++c) {
            float4 a = f0v[(size_t)c * hw4 + idx];
            float4 b = f1v[(size_t)c * hw4 + idx];
            float e0 = a.x - b.x + EPS, e1 = a.y - b.y + EPS;
            float e2 = a.z - b.z + EPS, e3 = a.w - b.w + EPS;
            s0 = fmaf(e0, e0, s0); s1 = fmaf(e1, e1, s1);
            s2 = fmaf(e2, e2, s2); s3 = fmaf(e3, e3, s3);
        }
        int4 g = ((const int4*)gt)[idx];
        float d[4] = { sqrtf(s0), sqrtf(s1), sqrtf(s2), sqrtf(s3) };
        int gg[4] = { g.x, g.y, g.z, g.w };
        int posc = 0;
        #pragma unroll
        for (int k = 0; k < 4; ++k) {
            posc += (gg[k] == 0) ? 1 : 0;
            float dd = d[k];
            if (dd <= 1.0f) {
                int bin = (int)(dd * (float)NUM_BINS);
                if (bin > NUM_BINS - 1) bin = NUM_BINS - 1;
                atomicAdd(&sh[bin + ((gg[k] != 0) ? NUM_BINS : 0)], 1u);
            }
        }
        if (posc) atomicAdd(&sh[2 * NUM_BINS], (unsigned)posc);
    }
    __syncthreads();
    for (int i = threadIdx.x; i < WS_WORDS; i += blockDim.x) {
        unsigned v = sh[i];
        if (v) atomicAdd(&ws[i], v);
    }
}

__global__ void hml_final(const unsigned int* __restrict__ ws,
                          float* __restrict__ out, int hw)
{
    __shared__ float terms[NUM_BINS];
    int i = threadIdx.x;
    unsigned pos = ws[2 * NUM_BINS];
    float pos_size = (float)pos;
    float neg_size = (float)(hw - (int)pos);
    if (i < NUM_BINS) {
        float hp = (float)ws[i] / pos_size;
        unsigned cn = ws[NUM_BINS + i];
        float hn = (float)cn / neg_size;
        terms[i] = (cn > 0u) ? hn * (logf(hn) - hp) : 0.0f;
    }
    __syncthreads();
    if (i == 0) {
        float s = 0.f;
        for (int k = 0; k < NUM_BINS; ++k) s += terms[k];
        out[0] = 1.0f + s / (float)NUM_BINS;
    }
}

extern "C" void kernel_launch(void* const* d_in, const int* in_sizes, int n_in,
                              void* d_out, int out_size, void* d_ws, size_t ws_size,
                              hipStream_t stream) {
    const float* f0 = (const float*)d_in[0];
    const float* f1 = (const float*)d_in[1];
    const int*   gt = (const int*)d_in[2];
    float* out = (float*)d_out;
    unsigned int* ws = (unsigned int*)d_ws;

    const int hw = in_sizes[2];          // h*w (= 1024*1024)
    const int C  = in_sizes[0] / hw;     // channels (= 32)

    hml_init_ws<<<1, 256, 0, stream>>>(ws);

    if (C == 32 && (hw & 511) == 0) {
        const int hw2 = hw >> 1;
        const int blocks = hw2 / 256;    // 2048 at 1024x1024
        hml_hist32<<<blocks, 256, 0, stream>>>(
            (const vfloat2*)f0, (const vfloat2*)f1, (const vint2*)gt, ws, hw2);
    } else {
        const int hw4 = hw >> 2;
        const int blocks = (hw4 + 255) / 256;
        hml_hist_generic<<<blocks, 256, 0, stream>>>(f0, f1, gt, ws, hw, C);
    }

    hml_final<<<1, 128, 0, stream>>>(ws, out, hw);
}

// Round 3
// 259.743 us; speedup vs baseline: 1.3566x; 1.3566x over previous
//
#include <hip/hip_runtime.h>
#include <math.h>

#define NUM_BINS 100
#define EPS 1e-6f

// ws layout (uint32): [0..99] pos-bin counts, [100..199] neg-bin counts, [200] pos pixel count
#define WS_WORDS (2 * NUM_BINS + 1)

// LDS: 8-way replicated histogram (R8: neutral, kept — zero cost insurance).
#define NREP 8
#define SH_POSC (2 * NUM_BINS * NREP)          // 1600
#define SH_WORDS (SH_POSC + 1)                 // 1601 words = 6.4 KB

// native vector types: __builtin_nontemporal_load requires these (not HIP_vector_type)
typedef float  vfloat4 __attribute__((ext_vector_type(4)));
typedef int    vint4   __attribute__((ext_vector_type(4)));

__global__ void hml_init_ws(unsigned int* __restrict__ ws) {
    int i = blockIdx.x * blockDim.x + threadIdx.x;
    if (i < WS_WORDS) ws[i] = 0u;
}

// C=32 specialized. R6: NT loads (bypass L1 miss-tracking cap, 106 -> <78us).
// R9 FAILED: __launch_bounds__(256,8) VGPR cap -> scratch spill of hoisted
//   load values (WRITE_SIZE 232 MB, 352us). Reverted.
// R10 single change vs R8: `#pragma unroll 1` on the channel-group loop.
//   Bounds live values to one 8-load batch (32 data VGPRs) WITHOUT an
//   allocation cap -> no spills possible; compiler VGPR should land ~48-64
//   -> 8 waves/SIMD (32 waves/CU, was ~4/SIMD with full unroll hoisting).
//   Clean occupancy probe: spill guard = WRITE_SIZE must stay KB-scale.
__global__ __launch_bounds__(256) void hml_hist32(
    const vfloat4* __restrict__ f0v, const vfloat4* __restrict__ f1v,
    const vint4* __restrict__ gt, unsigned int* __restrict__ ws, int hw4)
{
    __shared__ unsigned int sh[SH_WORDS];
    for (int i = threadIdx.x; i < SH_WORDS; i += 256) sh[i] = 0u;
    __syncthreads();

    const int idx = blockIdx.x * 256 + threadIdx.x;
    const int col = threadIdx.x & (NREP - 1);

    vint4 g = __builtin_nontemporal_load(&gt[idx]);
    float s0 = 0.f, s1 = 0.f, s2 = 0.f, s3 = 0.f;

    #pragma unroll 1
    for (int cg = 0; cg < 32; cg += 4) {
        vfloat4 a[4], b[4];
        #pragma unroll
        for (int j = 0; j < 4; ++j)
            a[j] = __builtin_nontemporal_load(&f0v[(size_t)(cg + j) * hw4 + idx]);
        #pragma unroll
        for (int j = 0; j < 4; ++j)
            b[j] = __builtin_nontemporal_load(&f1v[(size_t)(cg + j) * hw4 + idx]);
        #pragma unroll
        for (int j = 0; j < 4; ++j) {
            float e0 = a[j].x - b[j].x + EPS;
            float e1 = a[j].y - b[j].y + EPS;
            float e2 = a[j].z - b[j].z + EPS;
            float e3 = a[j].w - b[j].w + EPS;
            s0 = fmaf(e0, e0, s0);
            s1 = fmaf(e1, e1, s1);
            s2 = fmaf(e2, e2, s2);
            s3 = fmaf(e3, e3, s3);
        }
    }

    float d[4] = { sqrtf(s0), sqrtf(s1), sqrtf(s2), sqrtf(s3) };
    int gg[4] = { g.x, g.y, g.z, g.w };

    // pos-pixel count: shfl-reduce per wave, one LDS atomic per wave
    int posc = (gg[0] == 0) + (gg[1] == 0) + (gg[2] == 0) + (gg[3] == 0);
    for (int off = 32; off > 0; off >>= 1)
        posc += __shfl_down(posc, off, 64);
    if ((threadIdx.x & 63) == 0 && posc)
        atomicAdd(&sh[SH_POSC], (unsigned)posc);

    #pragma unroll
    for (int k = 0; k < 4; ++k) {
        float dd = d[k];
        // histc: values in [0,1] only (dd>=0 from sqrt); floor(d*100) clip 99
        if (dd <= 1.0f) {
            int bin = (int)(dd * (float)NUM_BINS);
            if (bin > NUM_BINS - 1) bin = NUM_BINS - 1;
            int logical = bin + ((gg[k] != 0) ? NUM_BINS : 0);
            atomicAdd(&sh[logical * NREP + col], 1u);
        }
    }

    __syncthreads();
    // flush: thread i (<200) merges the 8 replicas of logical bin i, one
    // global atomic per nonzero bin; thread 200 flushes the pos count.
    {
        int i = threadIdx.x;
        if (i < 2 * NUM_BINS) {
            unsigned v = 0;
            #pragma unroll
            for (int c = 0; c < NREP; ++c) v += sh[i * NREP + c];
            if (v) atomicAdd(&ws[i], v);
        } else if (i == 2 * NUM_BINS) {
            unsigned v = sh[SH_POSC];
            if (v) atomicAdd(&ws[2 * NUM_BINS], v);
        }
    }
}

// Generic fallback (any C, hw multiple of 4).
__global__ __launch_bounds__(256) void hml_hist_generic(
    const float* __restrict__ f0, const float* __restrict__ f1,
    const int* __restrict__ gt, unsigned int* __restrict__ ws,
    int hw, int C)
{
    __shared__ unsigned int sh[WS_WORDS];
    for (int i = threadIdx.x; i < WS_WORDS; i += blockDim.x) sh[i] = 0u;
    __syncthreads();

    const int hw4 = hw >> 2;
    const int idx = blockIdx.x * blockDim.x + threadIdx.x;

    if (idx < hw4) {
        const float4* __restrict__ f0v = (const float4*)f0;
        const float4* __restrict__ f1v = (const float4*)f1;
        float s0 = 0.f, s1 = 0.f, s2 = 0.f, s3 = 0.f;
        for (int c = 0; c < C; ++c) {
            float4 a = f0v[(size_t)c * hw4 + idx];
            float4 b = f1v[(size_t)c * hw4 + idx];
            float e0 = a.x - b.x + EPS, e1 = a.y - b.y + EPS;
            float e2 = a.z - b.z + EPS, e3 = a.w - b.w + EPS;
            s0 = fmaf(e0, e0, s0); s1 = fmaf(e1, e1, s1);
            s2 = fmaf(e2, e2, s2); s3 = fmaf(e3, e3, s3);
        }
        int4 g = ((const int4*)gt)[idx];
        float d[4] = { sqrtf(s0), sqrtf(s1), sqrtf(s2), sqrtf(s3) };
        int gg[4] = { g.x, g.y, g.z, g.w };
        int posc = 0;
        #pragma unroll
        for (int k = 0; k < 4; ++k) {
            posc += (gg[k] == 0) ? 1 : 0;
            float dd = d[k];
            if (dd <= 1.0f) {
                int bin = (int)(dd * (float)NUM_BINS);
                if (bin > NUM_BINS - 1) bin = NUM_BINS - 1;
                atomicAdd(&sh[bin + ((gg[k] != 0) ? NUM_BINS : 0)], 1u);
            }
        }
        if (posc) atomicAdd(&sh[2 * NUM_BINS], (unsigned)posc);
    }
    __syncthreads();
    for (int i = threadIdx.x; i < WS_WORDS; i += blockDim.x) {
        unsigned v = sh[i];
        if (v) atomicAdd(&ws[i], v);
    }
}

__global__ void hml_final(const unsigned int* __restrict__ ws,
                          float* __restrict__ out, int hw)
{
    __shared__ float terms[NUM_BINS];
    int i = threadIdx.x;
    unsigned pos = ws[2 * NUM_BINS];
    float pos_size = (float)pos;
    float neg_size = (float)(hw - (int)pos);
    if (i < NUM_BINS) {
        float hp = (float)ws[i] / pos_size;
        unsigned cn = ws[NUM_BINS + i];
        float hn = (float)cn / neg_size;
        terms[i] = (cn > 0u) ? hn * (logf(hn) - hp) : 0.0f;
    }
    __syncthreads();
    if (i == 0) {
        float s = 0.f;
        for (int k = 0; k < NUM_BINS; ++k) s += terms[k];
        out[0] = 1.0f + s / (float)NUM_BINS;
    }
}

extern "C" void kernel_launch(void* const* d_in, const int* in_sizes, int n_in,
                              void* d_out, int out_size, void* d_ws, size_t ws_size,
                              hipStream_t stream) {
    const float* f0 = (const float*)d_in[0];
    const float* f1 = (const float*)d_in[1];
    const int*   gt = (const int*)d_in[2];
    float* out = (float*)d_out;
    unsigned int* ws = (unsigned int*)d_ws;

    const int hw = in_sizes[2];          // h*w (= 1024*1024)
    const int C  = in_sizes[0] / hw;     // channels (= 32)

    hml_init_ws<<<1, 256, 0, stream>>>(ws);

    if (C == 32 && (hw & 1023) == 0) {
        const int hw4 = hw >> 2;
        const int blocks = hw4 / 256;    // 1024 at 1024x1024
        hml_hist32<<<blocks, 256, 0, stream>>>(
            (const vfloat4*)f0, (const vfloat4*)f1, (const vint4*)gt, ws, hw4);
    } else {
        const int hw4 = hw >> 2;
        const int blocks = (hw4 + 255) / 256;
        hml_hist_generic<<<blocks, 256, 0, stream>>>(f0, f1, gt, ws, hw, C);
    }

    hml_final<<<1, 128, 0, stream>>>(ws, out, hw);
}